// Round 1
// baseline (1479.654 us; speedup 1.0000x reference)
//
#include <hip/hip_runtime.h>

// SelMaxPool: pooled[m][c] = max( max_{i in cluster m} x[i][c],
//                                 max_{edges e: sel[e]<ks^2, cluster[dst[e]]==m} x[src[e]][c] )
// Strategy: d_out holds a sortable-uint-encoded running max. Three kernels:
//   1) init with per-cluster own-feature max (cluster = i/POOL by construction)
//   2) edge scatter via integer atomicMax (order-isomorphic float encoding)
//   3) in-place decode back to float.
// C is fixed at 64 by the reference (16 float4 chunks per row).

__device__ __forceinline__ unsigned enc_f(float f) {
    unsigned b = __float_as_uint(f);
    return (b & 0x80000000u) ? ~b : (b | 0x80000000u);
}
__device__ __forceinline__ float dec_f(unsigned u) {
    unsigned b = (u & 0x80000000u) ? (u & 0x7fffffffu) : ~u;
    return __uint_as_float(b);
}

__global__ void pool_init_kernel(const float* __restrict__ x,
                                 unsigned* __restrict__ out_u,
                                 int M, int pool) {
    int idx = blockIdx.x * blockDim.x + threadIdx.x;   // one per (m, c4)
    int total = M * 16;
    if (idx >= total) return;
    int m  = idx >> 4;
    int c4 = idx & 15;
    const float4* x4 = (const float4*)x;
    size_t base = (size_t)m * pool;
    float4 v = x4[base * 16 + c4];
    for (int k = 1; k < pool; ++k) {
        float4 w = x4[(base + k) * 16 + c4];
        v.x = fmaxf(v.x, w.x); v.y = fmaxf(v.y, w.y);
        v.z = fmaxf(v.z, w.z); v.w = fmaxf(v.w, w.w);
    }
    uint4 u;
    u.x = enc_f(v.x); u.y = enc_f(v.y); u.z = enc_f(v.z); u.w = enc_f(v.w);
    ((uint4*)out_u)[idx] = u;
}

__global__ void edge_scatter_kernel(const float* __restrict__ x,
                                    const int* __restrict__ edge_index,
                                    const int* __restrict__ selections,
                                    const int* __restrict__ cluster,
                                    const int* __restrict__ ksz,
                                    unsigned* __restrict__ out_u,
                                    int E) {
    int t = blockIdx.x * blockDim.x + threadIdx.x;     // 16 lanes per edge
    int e = t >> 4;
    if (e >= E) return;
    int c4 = t & 15;
    int ks = ksz[0];
    if (selections[e] >= ks * ks) return;              // out-of-window: loses to own x
    int src = edge_index[e];
    int dst = edge_index[E + e];
    int m = cluster[dst];
    float4 v = ((const float4*)x)[(size_t)src * 16 + c4];
    unsigned* o = out_u + (size_t)m * 64 + c4 * 4;
    atomicMax(o + 0, enc_f(v.x));
    atomicMax(o + 1, enc_f(v.y));
    atomicMax(o + 2, enc_f(v.z));
    atomicMax(o + 3, enc_f(v.w));
}

__global__ void decode_kernel(unsigned* __restrict__ out_u, int total4) {
    int idx = blockIdx.x * blockDim.x + threadIdx.x;
    if (idx >= total4) return;
    uint4 u = ((uint4*)out_u)[idx];
    float4 f;
    f.x = dec_f(u.x); f.y = dec_f(u.y); f.z = dec_f(u.z); f.w = dec_f(u.w);
    ((float4*)out_u)[idx] = f;
}

extern "C" void kernel_launch(void* const* d_in, const int* in_sizes, int n_in,
                              void* d_out, int out_size, void* d_ws, size_t ws_size,
                              hipStream_t stream) {
    const float* x          = (const float*)d_in[0];
    const int*   edge_index = (const int*)d_in[1];
    const int*   selections = (const int*)d_in[2];
    const int*   cluster    = (const int*)d_in[3];
    const int*   ksz        = (const int*)d_in[4];
    unsigned*    out_u      = (unsigned*)d_out;

    const int C = 64;
    int N = in_sizes[0] / C;
    int E = in_sizes[1] / 2;
    int M = out_size / C;
    int pool = N / M;                                  // 4

    int t1 = M * 16;                                   // (m, c4) pairs
    pool_init_kernel<<<(t1 + 255) / 256, 256, 0, stream>>>(x, out_u, M, pool);

    long long t2 = (long long)E * 16;
    edge_scatter_kernel<<<(int)((t2 + 255) / 256), 256, 0, stream>>>(
        x, edge_index, selections, cluster, ksz, out_u, E);

    decode_kernel<<<(t1 + 255) / 256, 256, 0, stream>>>(out_u, t1);
}

// Round 2
// 705.578 us; speedup vs baseline: 2.0971x; 2.0971x over previous
//
#include <hip/hip_runtime.h>

// SelMaxPool: pooled[m][c] = max( max_{i in cluster m} x[i][c],
//                                 max_{edges e: sel[e]<ks^2, cluster[dst[e]]==m} x[src[e]][c] )
// d_out holds a sortable-uint-encoded running max. Three kernels:
//   1) init with per-cluster own-feature max (cluster = i/POOL by construction)
//   2) edge scatter: check-then-atomicMax (stale reads are safe — max is monotone,
//      a stale/smaller value only causes a redundant atomic, never a missed one)
//   3) in-place decode back to float.
// C fixed at 64 by the reference (16 float4 chunks per row).

__device__ __forceinline__ unsigned enc_f(float f) {
    unsigned b = __float_as_uint(f);
    return (b & 0x80000000u) ? ~b : (b | 0x80000000u);
}
__device__ __forceinline__ float dec_f(unsigned u) {
    unsigned b = (u & 0x80000000u) ? (u & 0x7fffffffu) : ~u;
    return __uint_as_float(b);
}

__global__ void pool_init_kernel(const float* __restrict__ x,
                                 unsigned* __restrict__ out_u,
                                 int M, int pool) {
    int idx = blockIdx.x * blockDim.x + threadIdx.x;   // one per (m, c4)
    int total = M * 16;
    if (idx >= total) return;
    int m  = idx >> 4;
    int c4 = idx & 15;
    const float4* x4 = (const float4*)x;
    size_t base = (size_t)m * pool;
    float4 v = x4[base * 16 + c4];
    for (int k = 1; k < pool; ++k) {
        float4 w = x4[(base + k) * 16 + c4];
        v.x = fmaxf(v.x, w.x); v.y = fmaxf(v.y, w.y);
        v.z = fmaxf(v.z, w.z); v.w = fmaxf(v.w, w.w);
    }
    uint4 u;
    u.x = enc_f(v.x); u.y = enc_f(v.y); u.z = enc_f(v.z); u.w = enc_f(v.w);
    ((uint4*)out_u)[idx] = u;
}

__global__ void edge_scatter_kernel(const float* __restrict__ x,
                                    const int* __restrict__ edge_index,
                                    const int* __restrict__ selections,
                                    const int* __restrict__ cluster,
                                    const int* __restrict__ ksz,
                                    unsigned* __restrict__ out_u,
                                    int E) {
    int t = blockIdx.x * blockDim.x + threadIdx.x;     // 16 lanes per edge
    int e = t >> 4;
    if (e >= E) return;
    int c4 = t & 15;
    int ks = ksz[0];
    if (selections[e] >= ks * ks) return;              // out-of-window: loses to own x
    int src = edge_index[e];
    int dst = edge_index[E + e];
    int m = cluster[dst];
    float4 v = ((const float4*)x)[(size_t)src * 16 + c4];
    unsigned e0 = enc_f(v.x), e1 = enc_f(v.y), e2 = enc_f(v.z), e3 = enc_f(v.w);
    unsigned* o = out_u + (size_t)m * 64 + c4 * 4;
    uint4 cur = *(const uint4*)o;                      // plain load; stale-safe
    if (e0 > cur.x) atomicMax(o + 0, e0);
    if (e1 > cur.y) atomicMax(o + 1, e1);
    if (e2 > cur.z) atomicMax(o + 2, e2);
    if (e3 > cur.w) atomicMax(o + 3, e3);
}

__global__ void decode_kernel(unsigned* __restrict__ out_u, int total4) {
    int idx = blockIdx.x * blockDim.x + threadIdx.x;
    if (idx >= total4) return;
    uint4 u = ((uint4*)out_u)[idx];
    float4 f;
    f.x = dec_f(u.x); f.y = dec_f(u.y); f.z = dec_f(u.z); f.w = dec_f(u.w);
    ((float4*)out_u)[idx] = f;
}

extern "C" void kernel_launch(void* const* d_in, const int* in_sizes, int n_in,
                              void* d_out, int out_size, void* d_ws, size_t ws_size,
                              hipStream_t stream) {
    const float* x          = (const float*)d_in[0];
    const int*   edge_index = (const int*)d_in[1];
    const int*   selections = (const int*)d_in[2];
    const int*   cluster    = (const int*)d_in[3];
    const int*   ksz        = (const int*)d_in[4];
    unsigned*    out_u      = (unsigned*)d_out;

    const int C = 64;
    int N = in_sizes[0] / C;
    int E = in_sizes[1] / 2;
    int M = out_size / C;
    int pool = N / M;                                  // 4

    int t1 = M * 16;                                   // (m, c4) pairs
    pool_init_kernel<<<(t1 + 255) / 256, 256, 0, stream>>>(x, out_u, M, pool);

    long long t2 = (long long)E * 16;
    edge_scatter_kernel<<<(int)((t2 + 255) / 256), 256, 0, stream>>>(
        x, edge_index, selections, cluster, ksz, out_u, E);

    decode_kernel<<<(t1 + 255) / 256, 256, 0, stream>>>(out_u, t1);
}

// Round 3
// 479.933 us; speedup vs baseline: 3.0830x; 1.4702x over previous
//
#include <hip/hip_runtime.h>

// SelMaxPool via destination-cluster binning (CSR counting sort), then an
// atomic-free gather with fused member-row init and plain float output.
//   A) hist: count in-window edges per cluster           (atomicAdd, 512 KB)
//   B) scan1/scan2/scan3: exclusive scan -> offsets + cursor copy
//   C) scatter: records[pos] = src for each in-window edge (CSR fill)
//   D) gather: one wave per cluster; 4 member rows + binned rows, lane
//      layout r=lane>>4 (row slot), c4=lane&15 (float4 chunk) -> 4 rows in
//      flight per load instr; shfl_xor(16,32) cross-reduce; one 256 B store.
// Fallback (ws too small): round-2 check-then-atomicMax path.

#define SCAN_BLOCK 256
#define NEG_FLT_MAX (-3.402823466e38f)

// ---------------- binned path ----------------

__global__ void hist_kernel(const int* __restrict__ edge_index,
                            const int* __restrict__ selections,
                            const int* __restrict__ cluster,
                            const int* __restrict__ ksz,
                            unsigned* __restrict__ count, int E) {
    int e = blockIdx.x * blockDim.x + threadIdx.x;
    if (e >= E) return;
    int ks = ksz[0];
    if (selections[e] >= ks * ks) return;
    int m = cluster[edge_index[E + e]];
    atomicAdd(&count[m], 1u);
}

__global__ void scan1_kernel(const unsigned* __restrict__ count,
                             unsigned* __restrict__ excl,
                             unsigned* __restrict__ bsum, int M) {
    __shared__ unsigned s[SCAN_BLOCK];
    int i = blockIdx.x * SCAN_BLOCK + threadIdx.x;
    unsigned v = (i < M) ? count[i] : 0u;
    s[threadIdx.x] = v;
    __syncthreads();
    for (int off = 1; off < SCAN_BLOCK; off <<= 1) {
        unsigned t = (threadIdx.x >= off) ? s[threadIdx.x - off] : 0u;
        __syncthreads();
        s[threadIdx.x] += t;
        __syncthreads();
    }
    if (i < M) excl[i] = s[threadIdx.x] - v;
    if (threadIdx.x == SCAN_BLOCK - 1) bsum[blockIdx.x] = s[threadIdx.x];
}

__global__ void scan2_kernel(unsigned* __restrict__ bsum, int n) {
    __shared__ unsigned s[SCAN_BLOCK];
    __shared__ unsigned carry;
    if (threadIdx.x == 0) carry = 0u;
    __syncthreads();
    for (int base = 0; base < n; base += SCAN_BLOCK) {
        int i = base + threadIdx.x;
        unsigned v = (i < n) ? bsum[i] : 0u;
        s[threadIdx.x] = v;
        __syncthreads();
        for (int off = 1; off < SCAN_BLOCK; off <<= 1) {
            unsigned t = (threadIdx.x >= off) ? s[threadIdx.x - off] : 0u;
            __syncthreads();
            s[threadIdx.x] += t;
            __syncthreads();
        }
        unsigned excl = s[threadIdx.x] - v + carry;
        if (i < n) bsum[i] = excl;
        __syncthreads();                       // all reads of carry done
        if (threadIdx.x == SCAN_BLOCK - 1) carry = excl + v;
        __syncthreads();                       // new carry visible
    }
}

__global__ void scan3_kernel(unsigned* __restrict__ excl,
                             const unsigned* __restrict__ bsum,
                             unsigned* __restrict__ cursor, int M) {
    int i = blockIdx.x * blockDim.x + threadIdx.x;
    if (i >= M) return;
    unsigned v = excl[i] + bsum[i / SCAN_BLOCK];
    excl[i] = v;
    cursor[i] = v;
}

__global__ void scatter_kernel(const int* __restrict__ edge_index,
                               const int* __restrict__ selections,
                               const int* __restrict__ cluster,
                               const int* __restrict__ ksz,
                               unsigned* __restrict__ cursor,
                               unsigned* __restrict__ records, int E) {
    int e = blockIdx.x * blockDim.x + threadIdx.x;
    if (e >= E) return;
    int ks = ksz[0];
    if (selections[e] >= ks * ks) return;
    int m = cluster[edge_index[E + e]];
    unsigned pos = atomicAdd(&cursor[m], 1u);
    records[pos] = (unsigned)edge_index[e];    // src node
}

__global__ __launch_bounds__(256) void gather_kernel(
        const float* __restrict__ x,
        const unsigned* __restrict__ records,
        const unsigned* __restrict__ offsets,
        const unsigned* __restrict__ count,
        float* __restrict__ out, int M, int pool) {
    int lane = threadIdx.x & 63;
    int wave = threadIdx.x >> 6;
    int m = blockIdx.x * 4 + wave;
    if (m >= M) return;
    int r  = lane >> 4;                        // row slot 0..3
    int c4 = lane & 15;                        // float4 chunk within row
    const float4* x4 = (const float4*)x;
    float4 acc = make_float4(NEG_FLT_MAX, NEG_FLT_MAX, NEG_FLT_MAX, NEG_FLT_MAX);
    // member rows (cluster = contiguous blocks of `pool` nodes)
    for (int k = r; k < pool; k += 4) {
        float4 v = x4[((size_t)m * pool + k) * 16 + c4];
        acc.x = fmaxf(acc.x, v.x); acc.y = fmaxf(acc.y, v.y);
        acc.z = fmaxf(acc.z, v.z); acc.w = fmaxf(acc.w, v.w);
    }
    unsigned start = offsets[m], cnt = count[m];
    for (unsigned base = 0; base + (unsigned)r < cnt; base += 4) {
        unsigned src = records[start + base + (unsigned)r];
        float4 v = x4[(size_t)src * 16 + c4];
        acc.x = fmaxf(acc.x, v.x); acc.y = fmaxf(acc.y, v.y);
        acc.z = fmaxf(acc.z, v.z); acc.w = fmaxf(acc.w, v.w);
    }
    // reduce across the 4 row-slot groups
    for (int off = 16; off < 64; off <<= 1) {
        acc.x = fmaxf(acc.x, __shfl_xor(acc.x, off, 64));
        acc.y = fmaxf(acc.y, __shfl_xor(acc.y, off, 64));
        acc.z = fmaxf(acc.z, __shfl_xor(acc.z, off, 64));
        acc.w = fmaxf(acc.w, __shfl_xor(acc.w, off, 64));
    }
    if (r == 0) ((float4*)out)[(size_t)m * 16 + c4] = acc;
}

// ---------------- fallback path (round-2, no workspace) ----------------

__device__ __forceinline__ unsigned enc_f(float f) {
    unsigned b = __float_as_uint(f);
    return (b & 0x80000000u) ? ~b : (b | 0x80000000u);
}
__device__ __forceinline__ float dec_f(unsigned u) {
    unsigned b = (u & 0x80000000u) ? (u & 0x7fffffffu) : ~u;
    return __uint_as_float(b);
}

__global__ void pool_init_kernel(const float* __restrict__ x,
                                 unsigned* __restrict__ out_u, int M, int pool) {
    int idx = blockIdx.x * blockDim.x + threadIdx.x;
    if (idx >= M * 16) return;
    int m = idx >> 4, c4 = idx & 15;
    const float4* x4 = (const float4*)x;
    size_t base = (size_t)m * pool;
    float4 v = x4[base * 16 + c4];
    for (int k = 1; k < pool; ++k) {
        float4 w = x4[(base + k) * 16 + c4];
        v.x = fmaxf(v.x, w.x); v.y = fmaxf(v.y, w.y);
        v.z = fmaxf(v.z, w.z); v.w = fmaxf(v.w, w.w);
    }
    uint4 u; u.x = enc_f(v.x); u.y = enc_f(v.y); u.z = enc_f(v.z); u.w = enc_f(v.w);
    ((uint4*)out_u)[idx] = u;
}

__global__ void edge_scatter_kernel(const float* __restrict__ x,
                                    const int* __restrict__ edge_index,
                                    const int* __restrict__ selections,
                                    const int* __restrict__ cluster,
                                    const int* __restrict__ ksz,
                                    unsigned* __restrict__ out_u, int E) {
    int t = blockIdx.x * blockDim.x + threadIdx.x;
    int e = t >> 4;
    if (e >= E) return;
    int c4 = t & 15;
    int ks = ksz[0];
    if (selections[e] >= ks * ks) return;
    int src = edge_index[e];
    int m = cluster[edge_index[E + e]];
    float4 v = ((const float4*)x)[(size_t)src * 16 + c4];
    unsigned e0 = enc_f(v.x), e1 = enc_f(v.y), e2 = enc_f(v.z), e3 = enc_f(v.w);
    unsigned* o = out_u + (size_t)m * 64 + c4 * 4;
    uint4 cur = *(const uint4*)o;
    if (e0 > cur.x) atomicMax(o + 0, e0);
    if (e1 > cur.y) atomicMax(o + 1, e1);
    if (e2 > cur.z) atomicMax(o + 2, e2);
    if (e3 > cur.w) atomicMax(o + 3, e3);
}

__global__ void decode_kernel(unsigned* __restrict__ out_u, int total4) {
    int idx = blockIdx.x * blockDim.x + threadIdx.x;
    if (idx >= total4) return;
    uint4 u = ((uint4*)out_u)[idx];
    float4 f; f.x = dec_f(u.x); f.y = dec_f(u.y); f.z = dec_f(u.z); f.w = dec_f(u.w);
    ((float4*)out_u)[idx] = f;
}

// ---------------- launch ----------------

extern "C" void kernel_launch(void* const* d_in, const int* in_sizes, int n_in,
                              void* d_out, int out_size, void* d_ws, size_t ws_size,
                              hipStream_t stream) {
    const float* x          = (const float*)d_in[0];
    const int*   edge_index = (const int*)d_in[1];
    const int*   selections = (const int*)d_in[2];
    const int*   cluster    = (const int*)d_in[3];
    const int*   ksz        = (const int*)d_in[4];

    const int C = 64;
    int N = in_sizes[0] / C;
    int E = in_sizes[1] / 2;
    int M = out_size / C;
    int pool = N / M;                          // 4

    int nblk1 = (M + SCAN_BLOCK - 1) / SCAN_BLOCK;

    // workspace layout (unsigned words)
    size_t off_count   = 0;
    size_t off_excl    = off_count + (size_t)M;
    size_t off_cursor  = off_excl  + (size_t)M;
    size_t off_bsum    = off_cursor + (size_t)M;
    size_t off_records = (off_bsum + (size_t)nblk1 + 63) & ~(size_t)63;
    size_t need_bytes  = (off_records + (size_t)E) * 4;

    if (ws_size >= need_bytes) {
        unsigned* ws      = (unsigned*)d_ws;
        unsigned* count   = ws + off_count;
        unsigned* excl    = ws + off_excl;
        unsigned* cursor  = ws + off_cursor;
        unsigned* bsum    = ws + off_bsum;
        unsigned* records = ws + off_records;
        float*    out     = (float*)d_out;

        hipMemsetAsync(count, 0, (size_t)M * 4, stream);
        hist_kernel<<<(E + 255) / 256, 256, 0, stream>>>(
            edge_index, selections, cluster, ksz, count, E);
        scan1_kernel<<<nblk1, SCAN_BLOCK, 0, stream>>>(count, excl, bsum, M);
        scan2_kernel<<<1, SCAN_BLOCK, 0, stream>>>(bsum, nblk1);
        scan3_kernel<<<(M + 255) / 256, 256, 0, stream>>>(excl, bsum, cursor, M);
        scatter_kernel<<<(E + 255) / 256, 256, 0, stream>>>(
            edge_index, selections, cluster, ksz, cursor, records, E);
        gather_kernel<<<(M + 3) / 4, 256, 0, stream>>>(
            x, records, excl, count, out, M, pool);
    } else {
        // fallback: no-workspace atomicMax path
        unsigned* out_u = (unsigned*)d_out;
        int t1 = M * 16;
        pool_init_kernel<<<(t1 + 255) / 256, 256, 0, stream>>>(x, out_u, M, pool);
        long long t2 = (long long)E * 16;
        edge_scatter_kernel<<<(int)((t2 + 255) / 256), 256, 0, stream>>>(
            x, edge_index, selections, cluster, ksz, out_u, E);
        decode_kernel<<<(t1 + 255) / 256, 256, 0, stream>>>(out_u, t1);
    }
}

// Round 4
// 387.740 us; speedup vs baseline: 3.8161x; 1.2378x over previous
//
#include <hip/hip_runtime.h>

// SelMaxPool via fixed-capacity destination-cluster bins (no scan):
//   A) memset: count[M] + overflow cursor = 0
//   B) bin_scatter: pos=atomicAdd(count[m]); pos<CAP -> records[m*CAP+pos]=src,
//      else overflow list (expected ~20 entries for Poisson(14.2) @ CAP>=32).
//      m = dst >> log2(pool) (cluster is i//pool by construction; array fallback).
//   C) gather: one wave per cluster. Bin loaded ONCE into registers
//      (lane-held, shfl-broadcast), pad lanes with member row index so
//      redundant max contributions are free -> divergence-free 2x-unrolled
//      loop with two independent x-row loads in flight (no dependent
//      records->x chain). Member rows fused. shfl_xor cross-reduce, 256B store.
//   D) fixup: CAS-float-max overflow entries into out (runs after gather).
// Fallback (ws too small): check-then-atomicMax path.
// C fixed at 64 by the reference (16 float4 chunks per row).

#define NEG_FLT_MAX (-3.402823466e38f)
#define OFL_CAP 8192

__device__ __forceinline__ float4 fmax4(float4 a, float4 b) {
    return make_float4(fmaxf(a.x, b.x), fmaxf(a.y, b.y),
                       fmaxf(a.z, b.z), fmaxf(a.w, b.w));
}

// ---------------- binned path ----------------

__global__ void bin_scatter_kernel(const int* __restrict__ edge_index,
                                   const int* __restrict__ selections,
                                   const int* __restrict__ cluster,
                                   const int* __restrict__ ksz,
                                   unsigned* __restrict__ count,
                                   unsigned* __restrict__ records,
                                   unsigned* __restrict__ ofl,   // [0]=cursor, pairs after
                                   int E, int cap, int shift) {
    int e = blockIdx.x * blockDim.x + threadIdx.x;
    if (e >= E) return;
    int ks = ksz[0];
    if (selections[e] >= ks * ks) return;
    int dst = edge_index[E + e];
    int m = (shift >= 0) ? (dst >> shift) : cluster[dst];
    unsigned src = (unsigned)edge_index[e];
    unsigned pos = atomicAdd(&count[m], 1u);
    if (pos < (unsigned)cap) {
        records[(size_t)m * cap + pos] = src;
    } else {
        unsigned idx = atomicAdd(&ofl[0], 1u);
        if (idx < OFL_CAP) { ofl[1 + 2 * idx] = (unsigned)m; ofl[2 + 2 * idx] = src; }
    }
}

__global__ __launch_bounds__(256) void gather_kernel(
        const float* __restrict__ x,
        const unsigned* __restrict__ records,
        const unsigned* __restrict__ count,
        float* __restrict__ out, int M, int pool, int cap) {
    int lane = threadIdx.x & 63;
    int wave = threadIdx.x >> 6;
    int m = blockIdx.x * 4 + wave;
    if (m >= M) return;
    int r  = lane >> 4;                        // row slot 0..3
    int c4 = lane & 15;                        // float4 chunk within row
    const float4* x4 = (const float4*)x;
    unsigned mbase = (unsigned)(m * pool);

    // load bin once; pad unused lanes with first member row (harmless for max)
    int cnt_c = min((int)count[m], cap);
    unsigned rec = mbase;
    if (lane < cnt_c) rec = records[(size_t)m * cap + lane];

    // member rows (cluster = contiguous blocks of `pool` nodes)
    float4 acc = make_float4(NEG_FLT_MAX, NEG_FLT_MAX, NEG_FLT_MAX, NEG_FLT_MAX);
    for (int k = r; k < pool; k += 4)
        acc = fmax4(acc, x4[((size_t)mbase + k) * 16 + c4]);

    // binned rows: shfl-broadcast indices, 2 independent loads per iteration
    for (int base = 0; base < cnt_c; base += 8) {
        unsigned s0 = (unsigned)__shfl((int)rec, base + r, 64);
        unsigned s1 = (unsigned)__shfl((int)rec, base + 4 + r, 64);
        float4 v0 = x4[(size_t)s0 * 16 + c4];
        float4 v1 = x4[(size_t)s1 * 16 + c4];
        acc = fmax4(acc, fmax4(v0, v1));
    }

    // reduce across the 4 row-slot groups
    for (int off = 16; off < 64; off <<= 1) {
        acc.x = fmaxf(acc.x, __shfl_xor(acc.x, off, 64));
        acc.y = fmaxf(acc.y, __shfl_xor(acc.y, off, 64));
        acc.z = fmaxf(acc.z, __shfl_xor(acc.z, off, 64));
        acc.w = fmaxf(acc.w, __shfl_xor(acc.w, off, 64));
    }
    if (r == 0) ((float4*)out)[(size_t)m * 16 + c4] = acc;
}

__global__ void fixup_kernel(const float* __restrict__ x,
                             const unsigned* __restrict__ ofl,
                             float* __restrict__ out) {
    int t = blockIdx.x * blockDim.x + threadIdx.x;
    int i = t >> 4;
    unsigned n = ofl[0];
    if (n > OFL_CAP) n = OFL_CAP;
    if (i >= (int)n) return;
    unsigned m   = ofl[1 + 2 * i];
    unsigned src = ofl[2 + 2 * i];
    int c4 = t & 15;
    float4 v = ((const float4*)x)[(size_t)src * 16 + c4];
    float* o = out + (size_t)m * 64 + c4 * 4;
    float vals[4] = {v.x, v.y, v.z, v.w};
    for (int k = 0; k < 4; ++k) {
        unsigned* a = (unsigned*)(o + k);
        unsigned old = *a;
        while (__uint_as_float(old) < vals[k]) {
            unsigned assumed = old;
            old = atomicCAS(a, assumed, __float_as_uint(vals[k]));
            if (old == assumed) break;
        }
    }
}

// ---------------- fallback path (no workspace) ----------------

__device__ __forceinline__ unsigned enc_f(float f) {
    unsigned b = __float_as_uint(f);
    return (b & 0x80000000u) ? ~b : (b | 0x80000000u);
}
__device__ __forceinline__ float dec_f(unsigned u) {
    unsigned b = (u & 0x80000000u) ? (u & 0x7fffffffu) : ~u;
    return __uint_as_float(b);
}

__global__ void pool_init_kernel(const float* __restrict__ x,
                                 unsigned* __restrict__ out_u, int M, int pool) {
    int idx = blockIdx.x * blockDim.x + threadIdx.x;
    if (idx >= M * 16) return;
    int m = idx >> 4, c4 = idx & 15;
    const float4* x4 = (const float4*)x;
    size_t base = (size_t)m * pool;
    float4 v = x4[base * 16 + c4];
    for (int k = 1; k < pool; ++k) v = fmax4(v, x4[(base + k) * 16 + c4]);
    uint4 u; u.x = enc_f(v.x); u.y = enc_f(v.y); u.z = enc_f(v.z); u.w = enc_f(v.w);
    ((uint4*)out_u)[idx] = u;
}

__global__ void edge_scatter_kernel(const float* __restrict__ x,
                                    const int* __restrict__ edge_index,
                                    const int* __restrict__ selections,
                                    const int* __restrict__ cluster,
                                    const int* __restrict__ ksz,
                                    unsigned* __restrict__ out_u, int E) {
    int t = blockIdx.x * blockDim.x + threadIdx.x;
    int e = t >> 4;
    if (e >= E) return;
    int c4 = t & 15;
    int ks = ksz[0];
    if (selections[e] >= ks * ks) return;
    int src = edge_index[e];
    int m = cluster[edge_index[E + e]];
    float4 v = ((const float4*)x)[(size_t)src * 16 + c4];
    unsigned e0 = enc_f(v.x), e1 = enc_f(v.y), e2 = enc_f(v.z), e3 = enc_f(v.w);
    unsigned* o = out_u + (size_t)m * 64 + c4 * 4;
    uint4 cur = *(const uint4*)o;
    if (e0 > cur.x) atomicMax(o + 0, e0);
    if (e1 > cur.y) atomicMax(o + 1, e1);
    if (e2 > cur.z) atomicMax(o + 2, e2);
    if (e3 > cur.w) atomicMax(o + 3, e3);
}

__global__ void decode_kernel(unsigned* __restrict__ out_u, int total4) {
    int idx = blockIdx.x * blockDim.x + threadIdx.x;
    if (idx >= total4) return;
    uint4 u = ((uint4*)out_u)[idx];
    float4 f; f.x = dec_f(u.x); f.y = dec_f(u.y); f.z = dec_f(u.z); f.w = dec_f(u.w);
    ((float4*)out_u)[idx] = f;
}

// ---------------- launch ----------------

extern "C" void kernel_launch(void* const* d_in, const int* in_sizes, int n_in,
                              void* d_out, int out_size, void* d_ws, size_t ws_size,
                              hipStream_t stream) {
    const float* x          = (const float*)d_in[0];
    const int*   edge_index = (const int*)d_in[1];
    const int*   selections = (const int*)d_in[2];
    const int*   cluster    = (const int*)d_in[3];
    const int*   ksz        = (const int*)d_in[4];

    const int C = 64;
    int N = in_sizes[0] / C;
    int E = in_sizes[1] / 2;
    int M = out_size / C;
    int pool = N / M;                          // 4

    int shift = -1;
    if (pool > 0 && (pool & (pool - 1)) == 0) {
        shift = 0;
        while ((1 << shift) < pool) ++shift;
    }

    // workspace layout (unsigned words): count[M] | ofl cursor+pairs | records
    size_t off_count   = 0;
    size_t off_ofl     = off_count + (size_t)M;            // 64B-aligned (M mult of 16)
    size_t off_records = (off_ofl + 1 + 2 * (size_t)OFL_CAP + 15) & ~(size_t)15;
    size_t fixed_bytes = off_records * 4;

    int cap = 0;
    if (ws_size > fixed_bytes)
        cap = (int)((ws_size - fixed_bytes) / ((size_t)M * 4));
    if (cap > 64) cap = 64;

    if (cap >= 16) {
        unsigned* ws      = (unsigned*)d_ws;
        unsigned* count   = ws + off_count;
        unsigned* ofl     = ws + off_ofl;
        unsigned* records = ws + off_records;
        float*    out     = (float*)d_out;

        // zero counts + overflow cursor (contiguous)
        hipMemsetAsync(count, 0, (size_t)M * 4 + 4 * (off_ofl - (size_t)M) + 4, stream);

        bin_scatter_kernel<<<(E + 255) / 256, 256, 0, stream>>>(
            edge_index, selections, cluster, ksz, count, records, ofl,
            E, cap, shift);
        gather_kernel<<<(M + 3) / 4, 256, 0, stream>>>(
            x, records, count, out, M, pool, cap);
        fixup_kernel<<<(OFL_CAP * 16) / 256, 256, 0, stream>>>(x, ofl, out);
    } else {
        // fallback: no-workspace atomicMax path
        unsigned* out_u = (unsigned*)d_out;
        int t1 = M * 16;
        pool_init_kernel<<<(t1 + 255) / 256, 256, 0, stream>>>(x, out_u, M, pool);
        long long t2 = (long long)E * 16;
        edge_scatter_kernel<<<(int)((t2 + 255) / 256), 256, 0, stream>>>(
            x, edge_index, selections, cluster, ksz, out_u, E);
        decode_kernel<<<(t1 + 255) / 256, 256, 0, stream>>>(out_u, t1);
    }
}